// Round 6
// baseline (1504.846 us; speedup 1.0000x reference)
//
#include <hip/hip_runtime.h>

#define HID  256
#define TT   2048
#define NB   128
#define NTHR 512

// DPP-based add of a rotated copy (VALU pipe, no LDS traffic).
// 0xB1 = quad_perm xor1, 0x4E = quad_perm xor2, 0x124 = row_ror:4, 0x128 = row_ror:8
template <int CTRL>
__device__ __forceinline__ float dpp_add(float v) {
    int t = __builtin_amdgcn_update_dpp(0, __float_as_int(v), CTRL, 0xF, 0xF, true);
    return v + __int_as_float(t);
}

__device__ __forceinline__ float tanh_fast(float x) {
    // tanh(x) = 1 - 2/(e^{2x}+1); exp inf/0 limits give +-1 correctly.
    float e = __expf(2.0f * x);
    float r = __builtin_amdgcn_rcpf(e + 1.0f);
    return fmaf(-2.0f, r, 1.0f);
}

// Persistent RNN: one block per batch row. thread (rg = tid>>4, c3 = tid&15)
// owns rows 8*rg..8*rg+7, cols 16*c3..16*c3+15 of W_hh in registers.
//
// Register-residency fight log:
//  r2: plain loads  -> VGPR=88, compiler remats W_hh loads from L2 every step
//  r4: volatile     -> VGPR=84, compiler SPILLS to scratch, re-reads from L2
//  both = 67 GB over kernel = ~40 TB/s = L2 ceiling = the actual bottleneck.
// Root cause: LLVM AMDGPU targets default occupancy (4 waves/EU -> 128-VGPR
// cap) unless waves/EU is pinned on BOTH ends; __launch_bounds__ sets only
// the min. amdgpu_waves_per_eu(2,2) pins the target -> 256-VGPR budget, and
// volatile loads stay remat-proof, so keeping 128 weights live is now the
// allocator's cheapest choice.
__global__ __launch_bounds__(NTHR)
__attribute__((amdgpu_waves_per_eu(2, 2)))
void rnn_persist(
    const float* __restrict__ x,      // [B, T, 1]
    const float* __restrict__ W_ih,   // [256, 1]
    const float* __restrict__ W_hh,   // [256, 256]
    const float* __restrict__ b_ih,   // [256]
    const float* __restrict__ b_hh,   // [256]
    const float* __restrict__ W_out,  // [1, 256]
    const float* __restrict__ b_out,  // [1]
    float* __restrict__ y)            // [B, T, 1]
{
    // h stored as 8 chunks of 32 floats, each chunk padded to 36 words:
    // 16 distinct read addrs, 2 per 4-bank group (2-way aliasing ~free m136).
    __shared__ __align__(16) float s_h[2][8 * 36];
    __shared__ float s_x[TT];
    __shared__ float s_part[2][8];

    const int tid  = threadIdx.x;
    const int c3   = tid & 15;   // col chunk (16 cols)
    const int rg   = tid >> 4;   // row group (8 rows), 0..31
    const int lane = tid & 63;
    const int wv   = tid >> 6;   // wave 0..7
    const int b    = blockIdx.x;

    // stage x row
    for (int k = tid; k < TT; k += NTHR) s_x[k] = x[(size_t)b * TT + k];

    // weights resident in registers — volatile loads are remat-proof
    float4 w[8][4];
    #pragma unroll
    for (int r = 0; r < 8; ++r) {
        const volatile float* wp = &W_hh[(8 * rg + r) * HID + 16 * c3];
        #pragma unroll
        for (int g = 0; g < 4; ++g) {
            w[r][g].x = wp[4 * g + 0];
            w[r][g].y = wp[4 * g + 1];
            w[r][g].z = wp[4 * g + 2];
            w[r][g].w = wp[4 * g + 3];
        }
    }

    const int   myrow = 8 * rg + (c3 & 7);   // row this lane finalizes
    const float wih   = W_ih[myrow];
    const float bias  = b_ih[myrow] + b_hh[myrow];
    const float wo_my = W_out[myrow];
    const float bout  = b_out[0];

    // h0 = 0
    if (tid < 256) {
        int wd = 36 * (tid >> 5) + (tid & 31);
        s_h[0][wd] = 0.0f;
        s_h[1][wd] = 0.0f;
    }
    __syncthreads();

    int p = 0;
    float* yrow = y + (size_t)b * TT;
    const int hwword = 36 * (myrow >> 5) + (myrow & 31);   // h write addr
    const int rdbase = 36 * (c3 >> 1) + 16 * (c3 & 1);     // h read base

    for (int step = 0; step <= TT; ++step) {
        // ---- finalize y_{step-1}: rotating wave sums the 8 per-wave partials
        if (step >= 1 && wv == ((step - 1) & 7)) {
            float pp = s_part[(step - 1) & 1][lane & 7];   // broadcast-pattern read
            pp = dpp_add<0xB1>(pp);
            pp = dpp_add<0x4E>(pp);
            pp = dpp_add<0x124>(pp);
            if (lane == 0) yrow[step - 1] = pp + bout;
        }
        if (step == TT) break;

        const float xt = s_x[step];
        const float* hb = &s_h[p][rdbase];
        const float4 h0 = *(const float4*)(hb);
        const float4 h1 = *(const float4*)(hb + 4);
        const float4 h2 = *(const float4*)(hb + 8);
        const float4 h3 = *(const float4*)(hb + 12);

        float acc[8];
        #pragma unroll
        for (int r = 0; r < 8; ++r) acc[r] = 0.0f;
        #pragma unroll
        for (int r = 0; r < 8; ++r) {
            acc[r] = fmaf(h0.x, w[r][0].x, acc[r]);
            acc[r] = fmaf(h0.y, w[r][0].y, acc[r]);
            acc[r] = fmaf(h0.z, w[r][0].z, acc[r]);
            acc[r] = fmaf(h0.w, w[r][0].w, acc[r]);
            acc[r] = fmaf(h1.x, w[r][1].x, acc[r]);
            acc[r] = fmaf(h1.y, w[r][1].y, acc[r]);
            acc[r] = fmaf(h1.z, w[r][1].z, acc[r]);
            acc[r] = fmaf(h1.w, w[r][1].w, acc[r]);
            acc[r] = fmaf(h2.x, w[r][2].x, acc[r]);
            acc[r] = fmaf(h2.y, w[r][2].y, acc[r]);
            acc[r] = fmaf(h2.z, w[r][2].z, acc[r]);
            acc[r] = fmaf(h2.w, w[r][2].w, acc[r]);
            acc[r] = fmaf(h3.x, w[r][3].x, acc[r]);
            acc[r] = fmaf(h3.y, w[r][3].y, acc[r]);
            acc[r] = fmaf(h3.z, w[r][3].z, acc[r]);
            acc[r] = fmaf(h3.w, w[r][3].w, acc[r]);
        }

        // reduce across the 16 col-chunk lanes (bits 0..3 of tid), pure DPP
        #pragma unroll
        for (int r = 0; r < 8; ++r) {
            acc[r] = dpp_add<0xB1>(acc[r]);   // xor1
            acc[r] = dpp_add<0x4E>(acc[r]);   // xor2
            acc[r] = dpp_add<0x124>(acc[r]);  // ror4
            acc[r] = dpp_add<0x128>(acc[r]);  // ror8 -> all 16 lanes have totals
        }

        // every lane picks its row total (select bits work for c3>=8 too)
        float s01 = (c3 & 1) ? acc[1] : acc[0];
        float s23 = (c3 & 1) ? acc[3] : acc[2];
        float s45 = (c3 & 1) ? acc[5] : acc[4];
        float s67 = (c3 & 1) ? acc[7] : acc[6];
        float sA  = (c3 & 2) ? s23 : s01;
        float sB  = (c3 & 2) ? s67 : s45;
        float dot = (c3 & 4) ? sB : sA;
        float hn  = tanh_fast(fmaf(xt, wih, bias) + dot);

        if (c3 < 8) s_h[p ^ 1][hwword] = hn;

        // symmetric per-wave y partial (no straggler): rows this wave owns
        float pv = (c3 < 8) ? hn * wo_my : 0.0f;
        pv = dpp_add<0xB1>(pv);
        pv = dpp_add<0x4E>(pv);
        pv = dpp_add<0x124>(pv);
        pv = dpp_add<0x128>(pv);
        pv += __shfl_xor(pv, 16);
        pv += __shfl_xor(pv, 32);
        if (lane == 0) s_part[step & 1][wv] = pv;

        __syncthreads();
        p ^= 1;
    }
}

extern "C" void kernel_launch(void* const* d_in, const int* in_sizes, int n_in,
                              void* d_out, int out_size, void* d_ws, size_t ws_size,
                              hipStream_t stream) {
    const float* x     = (const float*)d_in[0];
    const float* W_ih  = (const float*)d_in[1];
    const float* W_hh  = (const float*)d_in[2];
    const float* b_ih  = (const float*)d_in[3];
    const float* b_hh  = (const float*)d_in[4];
    const float* W_out = (const float*)d_in[5];
    const float* b_out = (const float*)d_in[6];
    float* y = (float*)d_out;

    hipLaunchKernelGGL(rnn_persist, dim3(NB), dim3(NTHR), 0, stream,
                       x, W_ih, W_hh, b_ih, b_hh, W_out, b_out, y);
}

// Round 7
// 1446.704 us; speedup vs baseline: 1.0402x; 1.0402x over previous
//
#include <hip/hip_runtime.h>

#define HID  256
#define TT   2048
#define NB   128
#define NTHR 512

// DPP-based add of a rotated copy (VALU pipe, no LDS traffic).
// 0xB1 = quad_perm xor1, 0x4E = quad_perm xor2, 0x124 = row_ror:4, 0x128 = row_ror:8
template <int CTRL>
__device__ __forceinline__ float dpp_add(float v) {
    int t = __builtin_amdgcn_update_dpp(0, __float_as_int(v), CTRL, 0xF, 0xF, true);
    return v + __int_as_float(t);
}

__device__ __forceinline__ float tanh_fast(float x) {
    float e = __expf(2.0f * x);
    float r = __builtin_amdgcn_rcpf(e + 1.0f);
    return fmaf(-2.0f, r, 1.0f);
}

// Register-residency fight log:
//  r2: plain float4 array        -> VGPR=88, loads remat'd from L2 every step
//  r4: volatile into float4 array-> VGPR=84, array spilled to scratch (L2)
//  r5: + waves_per_eu(2,2)       -> VGPR=88, SGPR 112: attribute applied, no change
//  => root cause is the AGGREGATE: w[8][4] is memory-backed (r3's asm error
//     "tied INDIRECT register inputs" = alloca), so RA never sees 128 live
//     scalars. Fix: 128 individually-NAMED scalar floats (pure SSA, no alloca
//     possible) + scalar asm pin (opaque def: no remat, no elimination).
//     Budget 256 VGPR via waves_per_eu(2,2); ~180 live -> no spill reason.

#define DECL_ROW(R) \
    float W##R##_0, W##R##_1, W##R##_2,  W##R##_3,  W##R##_4,  W##R##_5,  W##R##_6,  W##R##_7, \
          W##R##_8, W##R##_9, W##R##_10, W##R##_11, W##R##_12, W##R##_13, W##R##_14, W##R##_15;

#define LOAD_ROW(R) do { \
    const float4* wp_ = (const float4*)&W_hh[(8 * rg + R) * HID + 16 * c3]; \
    float4 a_ = wp_[0], b_ = wp_[1], c_ = wp_[2], d_ = wp_[3]; \
    W##R##_0  = a_.x; W##R##_1  = a_.y; W##R##_2  = a_.z; W##R##_3  = a_.w; \
    W##R##_4  = b_.x; W##R##_5  = b_.y; W##R##_6  = b_.z; W##R##_7  = b_.w; \
    W##R##_8  = c_.x; W##R##_9  = c_.y; W##R##_10 = c_.z; W##R##_11 = c_.w; \
    W##R##_12 = d_.x; W##R##_13 = d_.y; W##R##_14 = d_.z; W##R##_15 = d_.w; \
} while (0)

#define PIN_ROW(R) asm volatile("" \
    : "+v"(W##R##_0),  "+v"(W##R##_1),  "+v"(W##R##_2),  "+v"(W##R##_3), \
      "+v"(W##R##_4),  "+v"(W##R##_5),  "+v"(W##R##_6),  "+v"(W##R##_7), \
      "+v"(W##R##_8),  "+v"(W##R##_9),  "+v"(W##R##_10), "+v"(W##R##_11), \
      "+v"(W##R##_12), "+v"(W##R##_13), "+v"(W##R##_14), "+v"(W##R##_15))

#define FMA_ROW(R) do { \
    acc##R = fmaf(hx0,  W##R##_0,  acc##R); \
    acc##R = fmaf(hx1,  W##R##_1,  acc##R); \
    acc##R = fmaf(hx2,  W##R##_2,  acc##R); \
    acc##R = fmaf(hx3,  W##R##_3,  acc##R); \
    acc##R = fmaf(hx4,  W##R##_4,  acc##R); \
    acc##R = fmaf(hx5,  W##R##_5,  acc##R); \
    acc##R = fmaf(hx6,  W##R##_6,  acc##R); \
    acc##R = fmaf(hx7,  W##R##_7,  acc##R); \
    acc##R = fmaf(hx8,  W##R##_8,  acc##R); \
    acc##R = fmaf(hx9,  W##R##_9,  acc##R); \
    acc##R = fmaf(hx10, W##R##_10, acc##R); \
    acc##R = fmaf(hx11, W##R##_11, acc##R); \
    acc##R = fmaf(hx12, W##R##_12, acc##R); \
    acc##R = fmaf(hx13, W##R##_13, acc##R); \
    acc##R = fmaf(hx14, W##R##_14, acc##R); \
    acc##R = fmaf(hx15, W##R##_15, acc##R); \
} while (0)

#define RED16(A) do { \
    A = dpp_add<0xB1>(A); A = dpp_add<0x4E>(A); \
    A = dpp_add<0x124>(A); A = dpp_add<0x128>(A); \
} while (0)

__global__ __launch_bounds__(NTHR)
__attribute__((amdgpu_waves_per_eu(2, 2)))
void rnn_persist(
    const float* __restrict__ x,      // [B, T, 1]
    const float* __restrict__ W_ih,   // [256, 1]
    const float* __restrict__ W_hh,   // [256, 256]
    const float* __restrict__ b_ih,   // [256]
    const float* __restrict__ b_hh,   // [256]
    const float* __restrict__ W_out,  // [1, 256]
    const float* __restrict__ b_out,  // [1]
    float* __restrict__ y)            // [B, T, 1]
{
    __shared__ __align__(16) float s_h[2][8 * 36];
    __shared__ float s_x[TT];
    __shared__ float s_part[2][8];

    const int tid  = threadIdx.x;
    const int c3   = tid & 15;   // col chunk (16 cols)
    const int rg   = tid >> 4;   // row group (8 rows), 0..31
    const int lane = tid & 63;
    const int wv   = tid >> 6;   // wave 0..7
    const int b    = blockIdx.x;

    for (int k = tid; k < TT; k += NTHR) s_x[k] = x[(size_t)b * TT + k];

    DECL_ROW(0) DECL_ROW(1) DECL_ROW(2) DECL_ROW(3)
    DECL_ROW(4) DECL_ROW(5) DECL_ROW(6) DECL_ROW(7)
    LOAD_ROW(0); LOAD_ROW(1); LOAD_ROW(2); LOAD_ROW(3);
    LOAD_ROW(4); LOAD_ROW(5); LOAD_ROW(6); LOAD_ROW(7);
    PIN_ROW(0); PIN_ROW(1); PIN_ROW(2); PIN_ROW(3);
    PIN_ROW(4); PIN_ROW(5); PIN_ROW(6); PIN_ROW(7);

    const int   myrow = 8 * rg + (c3 & 7);   // row this lane finalizes
    const float wih   = W_ih[myrow];
    const float bias  = b_ih[myrow] + b_hh[myrow];
    const float wo_my = W_out[myrow];
    const float bout  = b_out[0];

    if (tid < 256) {
        int wd = 36 * (tid >> 5) + (tid & 31);
        s_h[0][wd] = 0.0f;
        s_h[1][wd] = 0.0f;
    }
    __syncthreads();

    int p = 0;
    float* yrow = y + (size_t)b * TT;
    const int hwword = 36 * (myrow >> 5) + (myrow & 31);   // h write addr
    const int rdbase = 36 * (c3 >> 1) + 16 * (c3 & 1);     // h read base

    for (int step = 0; step <= TT; ++step) {
        // finalize y_{step-1}: rotating wave sums the 8 per-wave partials
        if (step >= 1 && wv == ((step - 1) & 7)) {
            float pp = s_part[(step - 1) & 1][lane & 7];
            pp = dpp_add<0xB1>(pp);
            pp = dpp_add<0x4E>(pp);
            pp = dpp_add<0x124>(pp);
            if (lane == 0) yrow[step - 1] = pp + bout;
        }
        if (step == TT) break;

        const float xt = s_x[step];
        const float* hb = &s_h[p][rdbase];
        const float4 H0 = *(const float4*)(hb);
        const float4 H1 = *(const float4*)(hb + 4);
        const float4 H2 = *(const float4*)(hb + 8);
        const float4 H3 = *(const float4*)(hb + 12);
        const float hx0 = H0.x, hx1 = H0.y, hx2  = H0.z, hx3  = H0.w;
        const float hx4 = H1.x, hx5 = H1.y, hx6  = H1.z, hx7  = H1.w;
        const float hx8 = H2.x, hx9 = H2.y, hx10 = H2.z, hx11 = H2.w;
        const float hx12 = H3.x, hx13 = H3.y, hx14 = H3.z, hx15 = H3.w;

        float acc0 = 0.0f, acc1 = 0.0f, acc2 = 0.0f, acc3 = 0.0f;
        float acc4 = 0.0f, acc5 = 0.0f, acc6 = 0.0f, acc7 = 0.0f;
        FMA_ROW(0); FMA_ROW(1); FMA_ROW(2); FMA_ROW(3);
        FMA_ROW(4); FMA_ROW(5); FMA_ROW(6); FMA_ROW(7);

        RED16(acc0); RED16(acc1); RED16(acc2); RED16(acc3);
        RED16(acc4); RED16(acc5); RED16(acc6); RED16(acc7);

        // every lane picks its row total (select bits work for c3>=8 too)
        float s01 = (c3 & 1) ? acc1 : acc0;
        float s23 = (c3 & 1) ? acc3 : acc2;
        float s45 = (c3 & 1) ? acc5 : acc4;
        float s67 = (c3 & 1) ? acc7 : acc6;
        float sA  = (c3 & 2) ? s23 : s01;
        float sB  = (c3 & 2) ? s67 : s45;
        float dot = (c3 & 4) ? sB : sA;
        float hn  = tanh_fast(fmaf(xt, wih, bias) + dot);

        if (c3 < 8) s_h[p ^ 1][hwword] = hn;

        // symmetric per-wave y partial (no straggler)
        float pv = (c3 < 8) ? hn * wo_my : 0.0f;
        pv = dpp_add<0xB1>(pv);
        pv = dpp_add<0x4E>(pv);
        pv = dpp_add<0x124>(pv);
        pv = dpp_add<0x128>(pv);
        pv += __shfl_xor(pv, 16);
        pv += __shfl_xor(pv, 32);
        if (lane == 0) s_part[step & 1][wv] = pv;

        __syncthreads();
        p ^= 1;
    }
}

extern "C" void kernel_launch(void* const* d_in, const int* in_sizes, int n_in,
                              void* d_out, int out_size, void* d_ws, size_t ws_size,
                              hipStream_t stream) {
    const float* x     = (const float*)d_in[0];
    const float* W_ih  = (const float*)d_in[1];
    const float* W_hh  = (const float*)d_in[2];
    const float* b_ih  = (const float*)d_in[3];
    const float* b_hh  = (const float*)d_in[4];
    const float* W_out = (const float*)d_in[5];
    const float* b_out = (const float*)d_in[6];
    float* y = (float*)d_out;

    hipLaunchKernelGGL(rnn_persist, dim3(NB), dim3(NTHR), 0, stream,
                       x, W_ih, W_hh, b_ih, b_hh, W_out, b_out, y);
}